// Round 6
// baseline (351.571 us; speedup 1.0000x reference)
//
#include <hip/hip_runtime.h>
#include <hip/hip_bf16.h>

#define NEX 4096
#define M   256
#define NM  (NEX*M)

typedef __attribute__((ext_vector_type(8))) short short8;
typedef __attribute__((ext_vector_type(4))) float floatx4;

__device__ inline unsigned short f2bfu(float x) {
    __hip_bfloat16 h = __float2bfloat16(x);
    union { __hip_bfloat16 b; unsigned short u; } cv; cv.b = h;
    return cv.u;
}
__device__ inline float bfu2f(unsigned short u) {
    union { unsigned short u; __hip_bfloat16 b; } cv; cv.u = u;
    return __bfloat162float(cv.b);
}

// swizzled element offset for [64][256] bf16 LDS tile, 16B-chunk XOR
__device__ inline int swz(int row, int col) {
    return row*256 + ((((col >> 3) ^ (row & 7)) << 3) | (col & 7));
}

// ---------------- fused prep kernel ----------------
__global__ void k_prep(const float* __restrict__ Wd, const float* __restrict__ W0,
                       const float* __restrict__ A,
                       unsigned short* __restrict__ WdHi, unsigned short* __restrict__ WdLo,
                       float* __restrict__ Wd0T, float* __restrict__ Wd1T,
                       float* __restrict__ W0T, float* __restrict__ symA,
                       float* __restrict__ ksq, float* __restrict__ trace) {
    int b = blockIdx.x, t = threadIdx.x;
    if (b < 512) {
        int idx = b*256 + t;
        float x = Wd[idx];
        unsigned short h = f2bfu(x);
        WdHi[idx] = h;
        WdLo[idx] = f2bfu(x - bfu2f(h));
    } else if (b < 768) {
        int idx = (b-512)*256 + t;          // dst index c*256+r
        int c = idx >> 8, r = idx & 255;
        Wd0T[idx] = Wd[r*256 + c];
    } else if (b < 1024) {
        int idx = (b-768)*256 + t;
        int c = idx >> 8, r = idx & 255;
        Wd1T[idx] = Wd[65536 + r*256 + c];
    } else if (b < 1088) {
        int idx = (b-1024)*256 + t;         // 16384 entries: c*256+r, c<64
        int c = idx >> 8, r = idx & 255;
        W0T[idx] = W0[r*64 + c];
    } else if (b == 1088) {
        float s = 0.f;
        for (int dd = 0; dd < 63; dd++) { float v = W0[t*64+dd]; s += v*v; }
        ksq[t] = s;
        float p = 0.f;
        for (int idx = t; idx < 630; idx += 256) {
            int r = idx / 63, i = idx % 63;
            float v = A[r*64+i]; p += v*v;
        }
        for (int off = 32; off; off >>= 1) p += __shfl_down(p, off, 64);
        __shared__ float red[4];
        if ((t & 63) == 0) red[t >> 6] = p;
        __syncthreads();
        if (t == 0) trace[0] = red[0]+red[1]+red[2]+red[3];
    } else {
        int idx = (b-1089)*256 + t;         // 4096 entries
        int i = idx >> 6, j = idx & 63;
        float s = 0.f;
        #pragma unroll
        for (int r = 0; r < 10; r++) s += A[r*64+i] * A[r*64+j];
        symA[idx] = s;
    }
}

// ---------------- fused forward chain: opening + pre0 + pre1 ----------------
__global__ void k_fwd(const float* __restrict__ x, const float* __restrict__ W0T,
                      const float* __restrict__ b0, const float* __restrict__ Wd0T,
                      const float* __restrict__ Wd1T, const float* __restrict__ bd,
                      float* __restrict__ tanhopen, float* __restrict__ tp0,
                      float* __restrict__ tp1) {
    __shared__ float xs[8*64];
    __shared__ float u0s[8*256];
    __shared__ float u1s[8*256];
    int n0 = blockIdx.x * 8, t = threadIdx.x;
    #pragma unroll
    for (int i = 0; i < 2; i++) { int f = t + i*256; xs[f] = x[n0*64 + f]; }
    __syncthreads();
    float acc[8];
    float b = b0[t];
    #pragma unroll
    for (int j = 0; j < 8; j++) acc[j] = b;
    for (int c = 0; c < 64; c++) {
        float w = W0T[c*256 + t];
        #pragma unroll
        for (int j = 0; j < 8; j++) acc[j] += w * xs[j*64 + c];
    }
    #pragma unroll
    for (int j = 0; j < 8; j++) {
        float p = acc[j];
        tanhopen[(n0+j)*256 + t] = tanhf(p);
        float a = fabsf(p);
        u0s[j*256 + t] = a + log1pf(expf(-2.f*a));
    }
    __syncthreads();
    b = bd[t];
    #pragma unroll
    for (int j = 0; j < 8; j++) acc[j] = b;
    for (int k = 0; k < 256; k++) {
        float w = Wd0T[k*256 + t];
        #pragma unroll
        for (int j = 0; j < 8; j++) acc[j] += w * u0s[j*256 + k];
    }
    #pragma unroll
    for (int j = 0; j < 8; j++) {
        float p = acc[j];
        tp0[(n0+j)*256 + t] = tanhf(p);
        float a = fabsf(p);
        u1s[j*256 + t] = u0s[j*256 + t] + 0.5f*(a + log1pf(expf(-2.f*a)));
    }
    __syncthreads();
    b = bd[256 + t];
    #pragma unroll
    for (int j = 0; j < 8; j++) acc[j] = b;
    for (int k = 0; k < 256; k++) {
        float w = Wd1T[k*256 + t];
        #pragma unroll
        for (int j = 0; j < 8; j++) acc[j] += w * u1s[j*256 + k];
    }
    #pragma unroll
    for (int j = 0; j < 8; j++) tp1[(n0+j)*256 + t] = tanhf(acc[j]);
}

// ---------------- fused backward chain: z2 + z1 + grad ----------------
__global__ void k_bwd(const float* __restrict__ tanhopen, const float* __restrict__ tp0,
                      const float* __restrict__ tp1, const float* __restrict__ wv,
                      const float* __restrict__ Wd, const float* __restrict__ W0,
                      const float* __restrict__ symA, const float* __restrict__ x,
                      const float* __restrict__ cw,
                      float* __restrict__ z2T, float* __restrict__ z1T,
                      float* __restrict__ out) {
    __shared__ float coefs[8*256];
    __shared__ float z2s[8*256];
    __shared__ float sa[64*64];
    __shared__ float xs[8*64];
    __shared__ float cws[64];
    const float* Wd0 = Wd;
    const float* Wd1 = Wd + 65536;
    int n0 = blockIdx.x * 8, t = threadIdx.x;
    float wvt = wv[t];
    #pragma unroll
    for (int j = 0; j < 8; j++) coefs[j*256 + t] = tp1[(n0+j)*256 + t] * wvt;
    #pragma unroll
    for (int i = 0; i < 16; i++) { int f = t + i*256; sa[f] = symA[f]; }
    #pragma unroll
    for (int i = 0; i < 2; i++) { int f = t + i*256; xs[f] = x[n0*64 + f]; }
    if (t < 64) cws[t] = cw[t];
    __syncthreads();
    float acc[8];
    #pragma unroll
    for (int j = 0; j < 8; j++) acc[j] = 0.f;
    for (int m = 0; m < 256; m++) {
        float w = Wd1[m*256 + t];
        #pragma unroll
        for (int j = 0; j < 8; j++) acc[j] += w * coefs[j*256 + m];
    }
    #pragma unroll
    for (int j = 0; j < 8; j++) {
        float v = wvt + 0.5f*acc[j];
        z2s[j*256 + t] = v;
        z2T[(n0+j)*256 + t] = v;
    }
    __syncthreads();
    #pragma unroll
    for (int j = 0; j < 8; j++) coefs[j*256 + t] = tp0[(n0+j)*256 + t] * z2s[j*256 + t];
    __syncthreads();
    #pragma unroll
    for (int j = 0; j < 8; j++) acc[j] = 0.f;
    for (int m = 0; m < 256; m++) {
        float w = Wd0[m*256 + t];
        #pragma unroll
        for (int j = 0; j < 8; j++) acc[j] += w * coefs[j*256 + m];
    }
    #pragma unroll
    for (int j = 0; j < 8; j++) {
        float v = z2s[j*256 + t] + 0.5f*acc[j];
        z2s[j*256 + t] = v;
        z1T[(n0+j)*256 + t] = v;
    }
    __syncthreads();
    #pragma unroll
    for (int j = 0; j < 8; j++) coefs[j*256 + t] = tanhopen[(n0+j)*256 + t] * z2s[j*256 + t];
    __syncthreads();
    int c = t & 63, jj = t >> 6;
    float g[2] = {0.f, 0.f};
    for (int m = 0; m < 256; m++) {
        float w0v = W0[m*64 + c];
        #pragma unroll
        for (int jb = 0; jb < 2; jb++) g[jb] += coefs[(jj + jb*4)*256 + m] * w0v;
    }
    #pragma unroll
    for (int jb = 0; jb < 2; jb++) {
        int j = jj + jb*4;
        float g2 = 0.f;
        for (int jd = 0; jd < 64; jd++) g2 += sa[jd*64 + c] * xs[j*64 + jd];
        out[(n0+j)*64 + c] = g[jb] + g2 + cws[c];
    }
}

// ---------------- heavy Jacobian kernel: 2 examples/block, pipelined ----------------
// 512 threads (8 waves), 2 examples per block. LDS: 2 swizzled JacT tiles (64 KB).
// KJ^T = Jac^T @ Wd^T : A = JacT (bf16 LDS), B = Wd hi/lo (global/L2, shared by both
// examples in registers). Wave w owns a-tiles {2w, 2w+1} for BOTH examples, all 4
// d-tiles -> acc[4][2][2] = 64 regs. 2-stage explicit register pipeline on A and B.
// C layout: col(a)=lane&15, row(d)=(lane>>4)*4+reg.

#define LOAD_B(SETH, SETL, KO) do {                                            \
    SETH[0] = *reinterpret_cast<const short8*>(Wh + aoff0 + (KO));             \
    SETL[0] = *reinterpret_cast<const short8*>(Wl + aoff0 + (KO));             \
    SETH[1] = *reinterpret_cast<const short8*>(Wh + aoff1 + (KO));             \
    SETL[1] = *reinterpret_cast<const short8*>(Wl + aoff1 + (KO));             \
} while (0)

#define LOAD_A(SET, KO) do {                                                   \
    _Pragma("unroll")                                                          \
    for (int e_ = 0; e_ < 2; ++e_) {                                           \
        _Pragma("unroll")                                                      \
        for (int c_ = 0; c_ < 4; ++c_)                                         \
            SET[e_][c_] = *reinterpret_cast<const short8*>(                    \
                &Jh[e_][swz(c_*16 + l15, (KO))]);                              \
    }                                                                          \
} while (0)

#define MFMA_PHASE(ASET, BSETH, BSETL) do {                                    \
    _Pragma("unroll")                                                          \
    for (int j_ = 0; j_ < 2; ++j_) {                                           \
        _Pragma("unroll")                                                      \
        for (int e_ = 0; e_ < 2; ++e_) {                                       \
            _Pragma("unroll")                                                  \
            for (int c_ = 0; c_ < 4; ++c_) {                                   \
                acc[c_][j_][e_] = __builtin_amdgcn_mfma_f32_16x16x32_bf16(     \
                    ASET[e_][c_], BSETH[j_], acc[c_][j_][e_], 0, 0, 0);        \
                acc[c_][j_][e_] = __builtin_amdgcn_mfma_f32_16x16x32_bf16(     \
                    ASET[e_][c_], BSETL[j_], acc[c_][j_][e_], 0, 0, 0);        \
            }                                                                  \
        }                                                                      \
    }                                                                          \
} while (0)

__global__ __launch_bounds__(512, 4) void k_heavy_mfma(
        const float* __restrict__ tanhopen, const float* __restrict__ tp0,
        const float* __restrict__ tp1, const float* __restrict__ z2T,
        const float* __restrict__ z1T, const float* __restrict__ wv,
        const float* __restrict__ W0T,
        const unsigned short* __restrict__ WdHi, const unsigned short* __restrict__ WdLo,
        const float* __restrict__ ksq, const float* __restrict__ trace,
        float* __restrict__ outTrH) {
    __shared__ __align__(16) unsigned short Jh[2][64*256];   // 64 KB
    __shared__ float ss[2][256], tp0s[2][256], w1s[2][256], w2s[2][256];
    __shared__ float red[8][2];
    int n0 = blockIdx.x * 2, t = threadIdx.x;        // t in [0,512)
    int lane = t & 63, w = t >> 6, l15 = lane & 15, lg = lane >> 4;

    float tot[2];
    {
        int e = t >> 8, m = t & 255;
        float sv   = tanhopen[(n0+e)*256 + m];
        float a0   = tp0[(n0+e)*256 + m];
        float a1   = tp1[(n0+e)*256 + m];
        ss[e][m]   = sv;
        tp0s[e][m] = a0;
        w1s[e][m]  = (1.f - a0*a0) * z2T[(n0+e)*256 + m];
        w2s[e][m]  = (1.f - a1*a1) * wv[m];
        float part = (1.f - sv*sv) * z1T[(n0+e)*256 + m] * ksq[m];  // layer-0 trH
        tot[0] = (e == 0) ? part : 0.f;
        tot[1] = (e == 0) ? 0.f : part;
    }
    __syncthreads();

    // build JacT[e][d][m] = W0T[d][m]*s[e][m] (bf16), row 63 zero.
    // thread t owns column-chunk m0 = (t&31)*8 (fixed -> ss read once), rows t>>5 + 16i
    {
        int m0 = (t & 31) << 3;
        int drow = t >> 5;                     // 0..15
        float se[2][8];
        #pragma unroll
        for (int e = 0; e < 2; ++e)
            #pragma unroll
            for (int q = 0; q < 8; ++q) se[e][q] = ss[e][m0 + q];
        #pragma unroll
        for (int i = 0; i < 8; ++i) {
            int e = i >> 2, d = drow + (i & 3)*16;
            short8 v8;
            if (d == 63) {
                #pragma unroll
                for (int q = 0; q < 8; ++q) v8[q] = 0;
            } else {
                const float* wp = &W0T[d*256 + m0];
                #pragma unroll
                for (int q = 0; q < 8; ++q) v8[q] = (short)f2bfu(wp[q] * se[e][q]);
            }
            *reinterpret_cast<short8*>(&Jh[e][swz(d, m0)]) = v8;
        }
    }
    __syncthreads();

    floatx4 acc[4][2][2];   // [d-tile c][a-tile j][example e]
    int aoff0 = ((w*2 + 0)*16 + l15) * 256;
    int aoff1 = ((w*2 + 1)*16 + l15) * 256;
    short8 A0_[2][4], A1_[2][4];
    short8 B0h[2], B0l[2], B1h[2], B1l[2];

    // ---------------- layer 0 ----------------
    {
        const unsigned short* Wh = WdHi;
        const unsigned short* Wl = WdLo;
        #pragma unroll
        for (int c = 0; c < 4; ++c)
            #pragma unroll
            for (int j = 0; j < 2; ++j)
                #pragma unroll
                for (int e = 0; e < 2; ++e)
                    acc[c][j][e] = (floatx4){0.f, 0.f, 0.f, 0.f};
        LOAD_B(B0h, B0l, lg*8);
        LOAD_A(A0_, lg*8);
        #pragma unroll
        for (int kk2 = 0; kk2 < 4; ++kk2) {
            { int ko = (2*kk2+1)*32 + lg*8; LOAD_B(B1h, B1l, ko); LOAD_A(A1_, ko); }
            MFMA_PHASE(A0_, B0h, B0l);
            if (kk2 < 3) { int ko = (2*kk2+2)*32 + lg*8; LOAD_B(B0h, B0l, ko); LOAD_A(A0_, ko); }
            MFMA_PHASE(A1_, B1h, B1l);
        }
    }
    __syncthreads();   // all layer-0 reads of Jh done before update writes

    // trH layer-1 term + Jac update (LDS RMW): JacT[e][d][a] += 0.5*tp0[e][a]*KJ1T
    {
        float w1a[2][2], tp0a[2][2]; int aidx[2];
        #pragma unroll
        for (int j = 0; j < 2; ++j) {
            aidx[j] = (w*2 + j)*16 + l15;
            #pragma unroll
            for (int e = 0; e < 2; ++e) {
                w1a[e][j]  = w1s[e][aidx[j]];
                tp0a[e][j] = 0.5f * tp0s[e][aidx[j]];
            }
        }
        #pragma unroll
        for (int c = 0; c < 4; ++c)
            #pragma unroll
            for (int r = 0; r < 4; ++r) {
                int d = c*16 + lg*4 + r;
                #pragma unroll
                for (int j = 0; j < 2; ++j) {
                    int off = swz(d, aidx[j]);
                    #pragma unroll
                    for (int e = 0; e < 2; ++e) {
                        float v = acc[c][j][e][r];
                        tot[e] += 0.5f * w1a[e][j] * v * v;
                        Jh[e][off] = f2bfu(bfu2f(Jh[e][off]) + tp0a[e][j] * v);
                    }
                }
            }
    }
    __syncthreads();   // updates visible before layer-1 reads

    // ---------------- layer 1 ----------------
    {
        const unsigned short* Wh = WdHi + 65536;
        const unsigned short* Wl = WdLo + 65536;
        #pragma unroll
        for (int c = 0; c < 4; ++c)
            #pragma unroll
            for (int j = 0; j < 2; ++j)
                #pragma unroll
                for (int e = 0; e < 2; ++e)
                    acc[c][j][e] = (floatx4){0.f, 0.f, 0.f, 0.f};
        LOAD_B(B0h, B0l, lg*8);
        LOAD_A(A0_, lg*8);
        #pragma unroll
        for (int kk2 = 0; kk2 < 4; ++kk2) {
            { int ko = (2*kk2+1)*32 + lg*8; LOAD_B(B1h, B1l, ko); LOAD_A(A1_, ko); }
            MFMA_PHASE(A0_, B0h, B0l);
            if (kk2 < 3) { int ko = (2*kk2+2)*32 + lg*8; LOAD_B(B0h, B0l, ko); LOAD_A(A0_, ko); }
            MFMA_PHASE(A1_, B1h, B1l);
        }
    }

    // trH layer-2 term
    {
        #pragma unroll
        for (int j = 0; j < 2; ++j) {
            int a = (w*2 + j)*16 + l15;
            #pragma unroll
            for (int e = 0; e < 2; ++e) {
                float w2a = w2s[e][a];
                #pragma unroll
                for (int c = 0; c < 4; ++c)
                    #pragma unroll
                    for (int r = 0; r < 4; ++r) {
                        float v = acc[c][j][e][r];
                        tot[e] += 0.5f * w2a * v * v;
                    }
            }
        }
    }

    // reduce 512 -> 2
    #pragma unroll
    for (int off2 = 32; off2; off2 >>= 1) {
        tot[0] += __shfl_down(tot[0], off2, 64);
        tot[1] += __shfl_down(tot[1], off2, 64);
    }
    if (lane == 0) { red[w][0] = tot[0]; red[w][1] = tot[1]; }
    __syncthreads();
    if (t < 2) {
        float s2 = trace[0];
        #pragma unroll
        for (int i = 0; i < 8; ++i) s2 += red[i][t];
        outTrH[n0 + t] = s2;
    }
}

// ---------------- launcher ----------------

extern "C" void kernel_launch(void* const* d_in, const int* in_sizes, int n_in,
                              void* d_out, int out_size, void* d_ws, size_t ws_size,
                              hipStream_t stream) {
    const float* x   = (const float*)d_in[0];   // 4096*64
    const float* W0  = (const float*)d_in[1];   // 256*64
    const float* b0  = (const float*)d_in[2];   // 256
    const float* Wd  = (const float*)d_in[3];   // 2*256*256
    const float* bd  = (const float*)d_in[4];   // 2*256
    const float* wv  = (const float*)d_in[5];   // 256
    const float* A   = (const float*)d_in[6];   // 10*64
    const float* cw  = (const float*)d_in[7];   // 64
    float* out = (float*)d_out;
    float* ws  = (float*)d_ws;

    float* tanhopen = ws;               // NM
    float* tp0  = tanhopen + NM;        // NM
    float* tp1  = tp0 + NM;             // NM
    float* z2T  = tp1 + NM;             // NM
    float* z1T  = z2T + NM;             // NM
    float* Wd0T = z1T + NM;             // 65536
    float* Wd1T = Wd0T + 65536;         // 65536
    float* W0T  = Wd1T + 65536;         // 16384
    float* symA = W0T + 16384;          // 4096
    float* ksq  = symA + 4096;          // 256
    float* trace= ksq + 256;            // 1
    unsigned short* WdHi = (unsigned short*)(trace + 1);  // 131072 ushorts
    unsigned short* WdLo = WdHi + 131072;                 // 131072 ushorts

    k_prep<<<1105, 256, 0, stream>>>(Wd, W0, A, WdHi, WdLo, Wd0T, Wd1T, W0T,
                                     symA, ksq, trace);
    k_fwd<<<NEX/8, 256, 0, stream>>>(x, W0T, b0, Wd0T, Wd1T, bd,
                                     tanhopen, tp0, tp1);
    k_bwd<<<NEX/8, 256, 0, stream>>>(tanhopen, tp0, tp1, wv, Wd, W0, symA, x, cw,
                                     z2T, z1T, out);
    k_heavy_mfma<<<NEX/2, 512, 0, stream>>>(tanhopen, tp0, tp1, z2T, z1T, wv,
                                            W0T, WdHi, WdLo, ksq, trace, out + NEX*64);
}

// Round 7
// 257.632 us; speedup vs baseline: 1.3646x; 1.3646x over previous
//
#include <hip/hip_runtime.h>
#include <hip/hip_bf16.h>

#define NEX 4096
#define M   256
#define NM  (NEX*M)

typedef __attribute__((ext_vector_type(8))) short short8;
typedef __attribute__((ext_vector_type(4))) float floatx4;

__device__ inline unsigned short f2bfu(float x) {
    __hip_bfloat16 h = __float2bfloat16(x);
    union { __hip_bfloat16 b; unsigned short u; } cv; cv.b = h;
    return cv.u;
}
__device__ inline float bfu2f(unsigned short u) {
    union { unsigned short u; __hip_bfloat16 b; } cv; cv.u = u;
    return __bfloat162float(cv.b);
}

// ---------------- fused prep kernel ----------------
// b in [0,256): Wd0T ; [256,512): Wd1T ; [512,576): W0T
// b == 576: ksq + trace ; [577,593): symA ; [593,657): FB fragment buffer
//
// FB layout (ushort): layer l (stride 131072 = 256 KB), chunk (atile,kk) of 1 KB:
//   FB[l*131072 + ((atile*8+kk)*2 + h)*512 + lane*8 + e]
//     = split_{h}( Wd[l][atile*16 + (lane&15)][kk*32 + (lane>>4)*8 + e] )
// i.e. exactly the 16 B each lane feeds to mfma as the B-operand -> wave loads are
// contiguous 1 KB.
__global__ void k_prep(const float* __restrict__ Wd, const float* __restrict__ W0,
                       const float* __restrict__ A,
                       unsigned short* __restrict__ FB,
                       float* __restrict__ Wd0T, float* __restrict__ Wd1T,
                       float* __restrict__ W0T, float* __restrict__ symA,
                       float* __restrict__ ksq, float* __restrict__ trace) {
    int b = blockIdx.x, t = threadIdx.x;
    if (b < 256) {
        int idx = b*256 + t;                // dst index c*256+r
        int c = idx >> 8, r = idx & 255;
        Wd0T[idx] = Wd[r*256 + c];
    } else if (b < 512) {
        int idx = (b-256)*256 + t;
        int c = idx >> 8, r = idx & 255;
        Wd1T[idx] = Wd[65536 + r*256 + c];
    } else if (b < 576) {
        int idx = (b-512)*256 + t;          // 16384 entries: c*256+r, c<64
        int c = idx >> 8, r = idx & 255;
        W0T[idx] = W0[r*64 + c];
    } else if (b == 576) {
        float s = 0.f;
        for (int dd = 0; dd < 63; dd++) { float v = W0[t*64+dd]; s += v*v; }
        ksq[t] = s;
        float p = 0.f;
        for (int idx = t; idx < 630; idx += 256) {
            int r = idx / 63, i = idx % 63;
            float v = A[r*64+i]; p += v*v;
        }
        for (int off = 32; off; off >>= 1) p += __shfl_down(p, off, 64);
        __shared__ float red[4];
        if ((t & 63) == 0) red[t >> 6] = p;
        __syncthreads();
        if (t == 0) trace[0] = red[0]+red[1]+red[2]+red[3];
    } else if (b < 593) {
        int idx = (b-577)*256 + t;          // 4096 entries
        int i = idx >> 6, j = idx & 63;
        float s = 0.f;
        #pragma unroll
        for (int r = 0; r < 10; r++) s += A[r*64+i] * A[r*64+j];
        symA[idx] = s;
    } else {
        // FB build: 256 (l,atile,kk) combos, 4 per block
        int combo = (b-593)*4 + (t >> 6);
        int l = combo >> 7, rest = combo & 127;
        int atile = rest >> 3, kk = rest & 7;
        int lane = t & 63, l15 = lane & 15, lg = lane >> 4;
        const float* src = Wd + l*65536 + (atile*16 + l15)*256 + kk*32 + lg*8;
        unsigned short* dst = FB + l*131072 + ((atile*8 + kk)*2)*512 + lane*8;
        #pragma unroll
        for (int e = 0; e < 8; ++e) {
            float x = src[e];
            unsigned short h = f2bfu(x);
            dst[e]       = h;
            dst[512 + e] = f2bfu(x - bfu2f(h));
        }
    }
}

// ---------------- fused forward chain: opening + pre0 + pre1 ----------------
__global__ void k_fwd(const float* __restrict__ x, const float* __restrict__ W0T,
                      const float* __restrict__ b0, const float* __restrict__ Wd0T,
                      const float* __restrict__ Wd1T, const float* __restrict__ bd,
                      float* __restrict__ tanhopen, float* __restrict__ tp0,
                      float* __restrict__ tp1) {
    __shared__ float xs[8*64];
    __shared__ float u0s[8*256];
    __shared__ float u1s[8*256];
    int n0 = blockIdx.x * 8, t = threadIdx.x;
    #pragma unroll
    for (int i = 0; i < 2; i++) { int f = t + i*256; xs[f] = x[n0*64 + f]; }
    __syncthreads();
    float acc[8];
    float b = b0[t];
    #pragma unroll
    for (int j = 0; j < 8; j++) acc[j] = b;
    for (int c = 0; c < 64; c++) {
        float w = W0T[c*256 + t];
        #pragma unroll
        for (int j = 0; j < 8; j++) acc[j] += w * xs[j*64 + c];
    }
    #pragma unroll
    for (int j = 0; j < 8; j++) {
        float p = acc[j];
        tanhopen[(n0+j)*256 + t] = tanhf(p);
        float a = fabsf(p);
        u0s[j*256 + t] = a + log1pf(expf(-2.f*a));
    }
    __syncthreads();
    b = bd[t];
    #pragma unroll
    for (int j = 0; j < 8; j++) acc[j] = b;
    for (int k = 0; k < 256; k++) {
        float w = Wd0T[k*256 + t];
        #pragma unroll
        for (int j = 0; j < 8; j++) acc[j] += w * u0s[j*256 + k];
    }
    #pragma unroll
    for (int j = 0; j < 8; j++) {
        float p = acc[j];
        tp0[(n0+j)*256 + t] = tanhf(p);
        float a = fabsf(p);
        u1s[j*256 + t] = u0s[j*256 + t] + 0.5f*(a + log1pf(expf(-2.f*a)));
    }
    __syncthreads();
    b = bd[256 + t];
    #pragma unroll
    for (int j = 0; j < 8; j++) acc[j] = b;
    for (int k = 0; k < 256; k++) {
        float w = Wd1T[k*256 + t];
        #pragma unroll
        for (int j = 0; j < 8; j++) acc[j] += w * u1s[j*256 + k];
    }
    #pragma unroll
    for (int j = 0; j < 8; j++) tp1[(n0+j)*256 + t] = tanhf(acc[j]);
}

// ---------------- fused backward chain: z2 + z1 + grad ----------------
__global__ void k_bwd(const float* __restrict__ tanhopen, const float* __restrict__ tp0,
                      const float* __restrict__ tp1, const float* __restrict__ wv,
                      const float* __restrict__ Wd, const float* __restrict__ W0,
                      const float* __restrict__ symA, const float* __restrict__ x,
                      const float* __restrict__ cw,
                      float* __restrict__ z2T, float* __restrict__ z1T,
                      float* __restrict__ out) {
    __shared__ float coefs[8*256];
    __shared__ float z2s[8*256];
    __shared__ float sa[64*64];
    __shared__ float xs[8*64];
    __shared__ float cws[64];
    const float* Wd0 = Wd;
    const float* Wd1 = Wd + 65536;
    int n0 = blockIdx.x * 8, t = threadIdx.x;
    float wvt = wv[t];
    #pragma unroll
    for (int j = 0; j < 8; j++) coefs[j*256 + t] = tp1[(n0+j)*256 + t] * wvt;
    #pragma unroll
    for (int i = 0; i < 16; i++) { int f = t + i*256; sa[f] = symA[f]; }
    #pragma unroll
    for (int i = 0; i < 2; i++) { int f = t + i*256; xs[f] = x[n0*64 + f]; }
    if (t < 64) cws[t] = cw[t];
    __syncthreads();
    float acc[8];
    #pragma unroll
    for (int j = 0; j < 8; j++) acc[j] = 0.f;
    for (int m = 0; m < 256; m++) {
        float w = Wd1[m*256 + t];
        #pragma unroll
        for (int j = 0; j < 8; j++) acc[j] += w * coefs[j*256 + m];
    }
    #pragma unroll
    for (int j = 0; j < 8; j++) {
        float v = wvt + 0.5f*acc[j];
        z2s[j*256 + t] = v;
        z2T[(n0+j)*256 + t] = v;
    }
    __syncthreads();
    #pragma unroll
    for (int j = 0; j < 8; j++) coefs[j*256 + t] = tp0[(n0+j)*256 + t] * z2s[j*256 + t];
    __syncthreads();
    #pragma unroll
    for (int j = 0; j < 8; j++) acc[j] = 0.f;
    for (int m = 0; m < 256; m++) {
        float w = Wd0[m*256 + t];
        #pragma unroll
        for (int j = 0; j < 8; j++) acc[j] += w * coefs[j*256 + m];
    }
    #pragma unroll
    for (int j = 0; j < 8; j++) {
        float v = z2s[j*256 + t] + 0.5f*acc[j];
        z2s[j*256 + t] = v;
        z1T[(n0+j)*256 + t] = v;
    }
    __syncthreads();
    #pragma unroll
    for (int j = 0; j < 8; j++) coefs[j*256 + t] = tanhopen[(n0+j)*256 + t] * z2s[j*256 + t];
    __syncthreads();
    int c = t & 63, jj = t >> 6;
    float g[2] = {0.f, 0.f};
    for (int m = 0; m < 256; m++) {
        float w0v = W0[m*64 + c];
        #pragma unroll
        for (int jb = 0; jb < 2; jb++) g[jb] += coefs[(jj + jb*4)*256 + m] * w0v;
    }
    #pragma unroll
    for (int jb = 0; jb < 2; jb++) {
        int j = jj + jb*4;
        float g2 = 0.f;
        for (int jd = 0; jd < 64; jd++) g2 += sa[jd*64 + c] * xs[j*64 + jd];
        out[(n0+j)*64 + c] = g[jb] + g2 + cws[c];
    }
}

// ---------------- heavy per-example Jacobian kernel (fragment-ordered operands) ----------------
// One block per example, 256 threads (4 waves). LDS: JacT in A-FRAGMENT order (32 KB):
//   Af[((c*8+kk)*64 + lane)*8 + e] = JacT[c*16 + (lane&15)][kk*32 + (lane>>4)*8 + e]
// -> MFMA A-reads are contiguous 1 KB wave-reads (conflict-free), B-reads from FB are
// contiguous 1 KB coalesced global loads (L2-resident). No gathers in the hot loop.
// Wave w owns a-tiles 4w..4w+3, all 4 d-tiles -> acc[4][4] (64 regs).
// C layout: col(a)=lane&15, row(d)=(lane>>4)*4+reg.
__global__ __launch_bounds__(256, 2) void k_heavy_mfma(
        const float* __restrict__ tanhopen, const float* __restrict__ tp0,
        const float* __restrict__ tp1, const float* __restrict__ z2T,
        const float* __restrict__ z1T, const float* __restrict__ wv,
        const float* __restrict__ W0T, const unsigned short* __restrict__ FB,
        const float* __restrict__ ksq, const float* __restrict__ trace,
        float* __restrict__ outTrH) {
    __shared__ __align__(16) unsigned short Af[64*256];   // 32 KB, fragment order
    __shared__ float ss[256], tp0s[256], w1s[256], w2s[256];
    __shared__ float red[4];
    int n = blockIdx.x, t = threadIdx.x;           // t in [0,256)
    int lane = t & 63, w = t >> 6, l15 = lane & 15, lg = lane >> 4;

    float sv   = tanhopen[n*256 + t];
    float tp0v = tp0[n*256 + t];
    float tp1v = tp1[n*256 + t];
    ss[t]   = sv;
    tp0s[t] = tp0v;
    w1s[t]  = (1.f - tp0v*tp0v) * z2T[n*256 + t];
    w2s[t]  = (1.f - tp1v*tp1v) * wv[t];
    float tot = (1.f - sv*sv) * z1T[n*256 + t] * ksq[t];   // trH layer-0 partial (m=t)
    __syncthreads();

    // build Af: chunk = c*512 + kk*64 + tl ; d = c*16 + (tl&15), m0 = kk*32 + (tl>>4)*8
    #pragma unroll
    for (int i = 0; i < 8; ++i) {
        int chunk = t + i*256;                 // 2048 chunks of 8 ushorts
        int c = chunk >> 9, kk = (chunk >> 6) & 7, tl = chunk & 63;
        int d = c*16 + (tl & 15);
        int m0 = kk*32 + (tl >> 4)*8;
        short8 v8;
        if (d == 63) {
            #pragma unroll
            for (int e = 0; e < 8; ++e) v8[e] = 0;
        } else {
            const float* wp = &W0T[d*256 + m0];
            #pragma unroll
            for (int e = 0; e < 8; ++e) v8[e] = (short)f2bfu(wp[e] * ss[m0 + e]);
        }
        *reinterpret_cast<short8*>(&Af[chunk*8]) = v8;
    }
    __syncthreads();

    floatx4 acc[4][4];   // [d-tile c][a-tile j]

    // ---------------- layer 0: KJ1^T ----------------
    #pragma unroll
    for (int c = 0; c < 4; ++c)
        #pragma unroll
        for (int j = 0; j < 4; ++j)
            acc[c][j] = (floatx4){0.f, 0.f, 0.f, 0.f};

    for (int kk = 0; kk < 8; ++kk) {
        short8 Ah[4];
        #pragma unroll
        for (int c = 0; c < 4; ++c)
            Ah[c] = *reinterpret_cast<const short8*>(&Af[((c*8 + kk)*64 + lane)*8]);
        #pragma unroll
        for (int j = 0; j < 4; ++j) {
            const unsigned short* bp = FB + (((w*4 + j)*8 + kk)*2)*512 + lane*8;
            short8 Bh = *reinterpret_cast<const short8*>(bp);
            short8 Bl = *reinterpret_cast<const short8*>(bp + 512);
            #pragma unroll
            for (int c = 0; c < 4; ++c) {
                acc[c][j] = __builtin_amdgcn_mfma_f32_16x16x32_bf16(Ah[c], Bh, acc[c][j], 0, 0, 0);
                acc[c][j] = __builtin_amdgcn_mfma_f32_16x16x32_bf16(Ah[c], Bl, acc[c][j], 0, 0, 0);
            }
        }
    }
    __syncthreads();   // all layer-0 reads of Af done before update writes

    // trH layer-1 term + Jac update (LDS RMW in fragment slot):
    //   JacT[d][a] += 0.5*tp0[a]*KJ1T[d][a]
    {
        float w1a[4], tp0a[4]; int aidx[4];
        #pragma unroll
        for (int j = 0; j < 4; ++j) {
            int a = (w*4 + j)*16 + l15;
            aidx[j] = a;
            w1a[j]  = w1s[a];
            tp0a[j] = 0.5f * tp0s[a];
        }
        #pragma unroll
        for (int c = 0; c < 4; ++c)
            #pragma unroll
            for (int r = 0; r < 4; ++r) {
                int d = c*16 + lg*4 + r;
                int dl = d & 15;
                #pragma unroll
                for (int j = 0; j < 4; ++j) {
                    float v = acc[c][j][r];
                    tot += 0.5f * w1a[j] * v * v;
                    int a = aidx[j];
                    int idx = ((c*8 + (a >> 5))*64 + (dl | (((a >> 3) & 3) << 4)))*8 + (a & 7);
                    Af[idx] = f2bfu(bfu2f(Af[idx]) + tp0a[j] * v);
                }
            }
    }
    __syncthreads();   // updates visible before layer-1 reads

    // ---------------- layer 1: KJ2^T ----------------
    #pragma unroll
    for (int c = 0; c < 4; ++c)
        #pragma unroll
        for (int j = 0; j < 4; ++j)
            acc[c][j] = (floatx4){0.f, 0.f, 0.f, 0.f};

    const unsigned short* FB1 = FB + 131072;
    for (int kk = 0; kk < 8; ++kk) {
        short8 Ah[4];
        #pragma unroll
        for (int c = 0; c < 4; ++c)
            Ah[c] = *reinterpret_cast<const short8*>(&Af[((c*8 + kk)*64 + lane)*8]);
        #pragma unroll
        for (int j = 0; j < 4; ++j) {
            const unsigned short* bp = FB1 + (((w*4 + j)*8 + kk)*2)*512 + lane*8;
            short8 Bh = *reinterpret_cast<const short8*>(bp);
            short8 Bl = *reinterpret_cast<const short8*>(bp + 512);
            #pragma unroll
            for (int c = 0; c < 4; ++c) {
                acc[c][j] = __builtin_amdgcn_mfma_f32_16x16x32_bf16(Ah[c], Bh, acc[c][j], 0, 0, 0);
                acc[c][j] = __builtin_amdgcn_mfma_f32_16x16x32_bf16(Ah[c], Bl, acc[c][j], 0, 0, 0);
            }
        }
    }

    // trH layer-2 term
    {
        float w2a[4];
        #pragma unroll
        for (int j = 0; j < 4; ++j) w2a[j] = w2s[(w*4 + j)*16 + l15];
        #pragma unroll
        for (int c = 0; c < 4; ++c)
            #pragma unroll
            for (int j = 0; j < 4; ++j)
                #pragma unroll
                for (int r = 0; r < 4; ++r) {
                    float v = acc[c][j][r];
                    tot += 0.5f * w2a[j] * v * v;
                }
    }

    // reduce 256 -> 1
    for (int off = 32; off; off >>= 1) tot += __shfl_down(tot, off, 64);
    if (lane == 0) red[w] = tot;
    __syncthreads();
    if (t == 0) outTrH[n] = red[0] + red[1] + red[2] + red[3] + trace[0];
}

// ---------------- launcher ----------------

extern "C" void kernel_launch(void* const* d_in, const int* in_sizes, int n_in,
                              void* d_out, int out_size, void* d_ws, size_t ws_size,
                              hipStream_t stream) {
    const float* x   = (const float*)d_in[0];   // 4096*64
    const float* W0  = (const float*)d_in[1];   // 256*64
    const float* b0  = (const float*)d_in[2];   // 256
    const float* Wd  = (const float*)d_in[3];   // 2*256*256
    const float* bd  = (const float*)d_in[4];   // 2*256
    const float* wv  = (const float*)d_in[5];   // 256
    const float* A   = (const float*)d_in[6];   // 10*64
    const float* cw  = (const float*)d_in[7];   // 64
    float* out = (float*)d_out;
    float* ws  = (float*)d_ws;

    float* tanhopen = ws;               // NM
    float* tp0  = tanhopen + NM;        // NM
    float* tp1  = tp0 + NM;             // NM
    float* z2T  = tp1 + NM;             // NM
    float* z1T  = z2T + NM;             // NM
    float* Wd0T = z1T + NM;             // 65536
    float* Wd1T = Wd0T + 65536;         // 65536
    float* W0T  = Wd1T + 65536;         // 16384
    float* symA = W0T + 16384;          // 4096
    float* ksq  = symA + 4096;          // 256
    float* trace= ksq + 256;            // 1
    unsigned short* FB = (unsigned short*)(trace + 1);    // 262144 ushorts (512 KB)

    k_prep<<<657, 256, 0, stream>>>(Wd, W0, A, FB, Wd0T, Wd1T, W0T,
                                    symA, ksq, trace);
    k_fwd<<<NEX/8, 256, 0, stream>>>(x, W0T, b0, Wd0T, Wd1T, bd,
                                     tanhopen, tp0, tp1);
    k_bwd<<<NEX/8, 256, 0, stream>>>(tanhopen, tp0, tp1, wv, Wd, W0, symA, x, cw,
                                     z2T, z1T, out);
    k_heavy_mfma<<<NEX, 256, 0, stream>>>(tanhopen, tp0, tp1, z2T, z1T, wv,
                                          W0T, FB, ksq, trace, out + NEX*64);
}

// Round 8
// 251.462 us; speedup vs baseline: 1.3981x; 1.0245x over previous
//
#include <hip/hip_runtime.h>
#include <hip/hip_bf16.h>

#define NEX 4096
#define M   256
#define NM  (NEX*M)

typedef __attribute__((ext_vector_type(8))) short short8;
typedef __attribute__((ext_vector_type(16))) float floatx16;

__device__ inline unsigned short f2bfu(float x) {
    __hip_bfloat16 h = __float2bfloat16(x);
    union { __hip_bfloat16 b; unsigned short u; } cv; cv.b = h;
    return cv.u;
}
__device__ inline float bfu2f(unsigned short u) {
    union { unsigned short u; __hip_bfloat16 b; } cv; cv.u = u;
    return __bfloat162float(cv.b);
}

// ---------------- fused prep kernel ----------------
// b in [0,256): Wd0T ; [256,512): Wd1T ; [512,576): W0T
// b == 576: ksq + trace ; [577,593): symA ; [593,657): FB fragment buffer
//
// FB layout for 32x32x16 MFMA B-operand (ushort), layer l stride 131072:
//   chunk (atile in [0,8), kstep in [0,16), h in {hi,lo}) of 512 ushorts:
//   FB[l*131072 + ((atile*16+kstep)*2 + h)*512 + lane*8 + e]
//     = split_h( Wd[l][atile*32 + (lane&31)][kstep*16 + (lane>>5)*8 + e] )
// -> wave B-loads are contiguous 1 KB.
__global__ void k_prep(const float* __restrict__ Wd, const float* __restrict__ W0,
                       const float* __restrict__ A,
                       unsigned short* __restrict__ FB,
                       float* __restrict__ Wd0T, float* __restrict__ Wd1T,
                       float* __restrict__ W0T, float* __restrict__ symA,
                       float* __restrict__ ksq, float* __restrict__ trace) {
    int b = blockIdx.x, t = threadIdx.x;
    if (b < 256) {
        int idx = b*256 + t;                // dst index c*256+r
        int c = idx >> 8, r = idx & 255;
        Wd0T[idx] = Wd[r*256 + c];
    } else if (b < 512) {
        int idx = (b-256)*256 + t;
        int c = idx >> 8, r = idx & 255;
        Wd1T[idx] = Wd[65536 + r*256 + c];
    } else if (b < 576) {
        int idx = (b-512)*256 + t;          // 16384 entries: c*256+r, c<64
        int c = idx >> 8, r = idx & 255;
        W0T[idx] = W0[r*64 + c];
    } else if (b == 576) {
        float s = 0.f;
        for (int dd = 0; dd < 63; dd++) { float v = W0[t*64+dd]; s += v*v; }
        ksq[t] = s;
        float p = 0.f;
        for (int idx = t; idx < 630; idx += 256) {
            int r = idx / 63, i = idx % 63;
            float v = A[r*64+i]; p += v*v;
        }
        for (int off = 32; off; off >>= 1) p += __shfl_down(p, off, 64);
        __shared__ float red[4];
        if ((t & 63) == 0) red[t >> 6] = p;
        __syncthreads();
        if (t == 0) trace[0] = red[0]+red[1]+red[2]+red[3];
    } else if (b < 593) {
        int idx = (b-577)*256 + t;          // 4096 entries
        int i = idx >> 6, j = idx & 63;
        float s = 0.f;
        #pragma unroll
        for (int r = 0; r < 10; r++) s += A[r*64+i] * A[r*64+j];
        symA[idx] = s;
    } else {
        // FB build: 256 (l,atile,kstep) combos, 4 per block
        int combo = (b-593)*4 + (t >> 6);
        int l = combo >> 7, rest = combo & 127;   // rest = atile*16 + kstep
        int atile = rest >> 4, kstep = rest & 15;
        int lane = t & 63, l31 = lane & 31, lhi = lane >> 5;
        const float* src = Wd + l*65536 + (atile*32 + l31)*256 + kstep*16 + lhi*8;
        unsigned short* dst = FB + l*131072 + ((atile*16 + kstep)*2)*512 + lane*8;
        #pragma unroll
        for (int e = 0; e < 8; ++e) {
            float x = src[e];
            unsigned short h = f2bfu(x);
            dst[e]       = h;
            dst[512 + e] = f2bfu(x - bfu2f(h));
        }
    }
}

// ---------------- fused forward chain: opening + pre0 + pre1 ----------------
__global__ void k_fwd(const float* __restrict__ x, const float* __restrict__ W0T,
                      const float* __restrict__ b0, const float* __restrict__ Wd0T,
                      const float* __restrict__ Wd1T, const float* __restrict__ bd,
                      float* __restrict__ tanhopen, float* __restrict__ tp0,
                      float* __restrict__ tp1) {
    __shared__ float xs[8*64];
    __shared__ float u0s[8*256];
    __shared__ float u1s[8*256];
    int n0 = blockIdx.x * 8, t = threadIdx.x;
    #pragma unroll
    for (int i = 0; i < 2; i++) { int f = t + i*256; xs[f] = x[n0*64 + f]; }
    __syncthreads();
    float acc[8];
    float b = b0[t];
    #pragma unroll
    for (int j = 0; j < 8; j++) acc[j] = b;
    for (int c = 0; c < 64; c++) {
        float w = W0T[c*256 + t];
        #pragma unroll
        for (int j = 0; j < 8; j++) acc[j] += w * xs[j*64 + c];
    }
    #pragma unroll
    for (int j = 0; j < 8; j++) {
        float p = acc[j];
        tanhopen[(n0+j)*256 + t] = tanhf(p);
        float a = fabsf(p);
        u0s[j*256 + t] = a + log1pf(expf(-2.f*a));
    }
    __syncthreads();
    b = bd[t];
    #pragma unroll
    for (int j = 0; j < 8; j++) acc[j] = b;
    for (int k = 0; k < 256; k++) {
        float w = Wd0T[k*256 + t];
        #pragma unroll
        for (int j = 0; j < 8; j++) acc[j] += w * u0s[j*256 + k];
    }
    #pragma unroll
    for (int j = 0; j < 8; j++) {
        float p = acc[j];
        tp0[(n0+j)*256 + t] = tanhf(p);
        float a = fabsf(p);
        u1s[j*256 + t] = u0s[j*256 + t] + 0.5f*(a + log1pf(expf(-2.f*a)));
    }
    __syncthreads();
    b = bd[256 + t];
    #pragma unroll
    for (int j = 0; j < 8; j++) acc[j] = b;
    for (int k = 0; k < 256; k++) {
        float w = Wd1T[k*256 + t];
        #pragma unroll
        for (int j = 0; j < 8; j++) acc[j] += w * u1s[j*256 + k];
    }
    #pragma unroll
    for (int j = 0; j < 8; j++) tp1[(n0+j)*256 + t] = tanhf(acc[j]);
}

// ---------------- fused backward chain: z2 + z1 + grad ----------------
__global__ void k_bwd(const float* __restrict__ tanhopen, const float* __restrict__ tp0,
                      const float* __restrict__ tp1, const float* __restrict__ wv,
                      const float* __restrict__ Wd, const float* __restrict__ W0,
                      const float* __restrict__ symA, const float* __restrict__ x,
                      const float* __restrict__ cw,
                      float* __restrict__ z2T, float* __restrict__ z1T,
                      float* __restrict__ out) {
    __shared__ float coefs[8*256];
    __shared__ float z2s[8*256];
    __shared__ float sa[64*64];
    __shared__ float xs[8*64];
    __shared__ float cws[64];
    const float* Wd0 = Wd;
    const float* Wd1 = Wd + 65536;
    int n0 = blockIdx.x * 8, t = threadIdx.x;
    float wvt = wv[t];
    #pragma unroll
    for (int j = 0; j < 8; j++) coefs[j*256 + t] = tp1[(n0+j)*256 + t] * wvt;
    #pragma unroll
    for (int i = 0; i < 16; i++) { int f = t + i*256; sa[f] = symA[f]; }
    #pragma unroll
    for (int i = 0; i < 2; i++) { int f = t + i*256; xs[f] = x[n0*64 + f]; }
    if (t < 64) cws[t] = cw[t];
    __syncthreads();
    float acc[8];
    #pragma unroll
    for (int j = 0; j < 8; j++) acc[j] = 0.f;
    for (int m = 0; m < 256; m++) {
        float w = Wd1[m*256 + t];
        #pragma unroll
        for (int j = 0; j < 8; j++) acc[j] += w * coefs[j*256 + m];
    }
    #pragma unroll
    for (int j = 0; j < 8; j++) {
        float v = wvt + 0.5f*acc[j];
        z2s[j*256 + t] = v;
        z2T[(n0+j)*256 + t] = v;
    }
    __syncthreads();
    #pragma unroll
    for (int j = 0; j < 8; j++) coefs[j*256 + t] = tp0[(n0+j)*256 + t] * z2s[j*256 + t];
    __syncthreads();
    #pragma unroll
    for (int j = 0; j < 8; j++) acc[j] = 0.f;
    for (int m = 0; m < 256; m++) {
        float w = Wd0[m*256 + t];
        #pragma unroll
        for (int j = 0; j < 8; j++) acc[j] += w * coefs[j*256 + m];
    }
    #pragma unroll
    for (int j = 0; j < 8; j++) {
        float v = z2s[j*256 + t] + 0.5f*acc[j];
        z2s[j*256 + t] = v;
        z1T[(n0+j)*256 + t] = v;
    }
    __syncthreads();
    #pragma unroll
    for (int j = 0; j < 8; j++) coefs[j*256 + t] = tanhopen[(n0+j)*256 + t] * z2s[j*256 + t];
    __syncthreads();
    int c = t & 63, jj = t >> 6;
    float g[2] = {0.f, 0.f};
    for (int m = 0; m < 256; m++) {
        float w0v = W0[m*64 + c];
        #pragma unroll
        for (int jb = 0; jb < 2; jb++) g[jb] += coefs[(jj + jb*4)*256 + m] * w0v;
    }
    #pragma unroll
    for (int jb = 0; jb < 2; jb++) {
        int j = jj + jb*4;
        float g2 = 0.f;
        for (int jd = 0; jd < 64; jd++) g2 += sa[jd*64 + c] * xs[j*64 + jd];
        out[(n0+j)*64 + c] = g[jb] + g2 + cws[c];
    }
}

// ---------------- heavy per-example Jacobian kernel (32x32x16 MFMA) ----------------
// One block per example, 256 threads (4 waves), 3 blocks/CU (LDS ~37 KB, cap 170 regs).
// KJ^T = Jac^T @ Wd^T : A = JacT (64x256 bf16, fragment-ordered LDS),
// B = Wd hi/lo (fragment-ordered global FB, L2-resident). 32x32x16 MFMA.
// Wave w owns a-tiles {2w,2w+1} (32 a's each) x both d-tiles -> acc[2][2] x 16 = 64 regs.
// A-frag: lane holds JacT[dtile*32+(lane&31)][kstep*16+(lane>>5)*8+e]
// B-frag: lane holds Wd[atile*32+(lane&31)][kstep*16+(lane>>5)*8+e]
// C/D:    col(a)=lane&31, row(d)=(reg&3)+8*(reg>>2)+4*(lane>>5)  [m74/m101-verified]
__global__ __launch_bounds__(256, 3) void k_heavy_mfma(
        const float* __restrict__ tanhopen, const float* __restrict__ tp0,
        const float* __restrict__ tp1, const float* __restrict__ z2T,
        const float* __restrict__ z1T, const float* __restrict__ wv,
        const float* __restrict__ W0T, const unsigned short* __restrict__ FB,
        const float* __restrict__ ksq, const float* __restrict__ trace,
        float* __restrict__ outTrH) {
    __shared__ __align__(16) unsigned short Af[2*16*512];   // 32 KB, fragment order
    __shared__ float ss[256], tp0s[256], w1s[256], w2s[256];
    __shared__ float red[4];
    int n = blockIdx.x, t = threadIdx.x;           // t in [0,256)
    int lane = t & 63, w = t >> 6, l31 = lane & 31, lhi = lane >> 5;

    float sv   = tanhopen[n*256 + t];
    float tp0v = tp0[n*256 + t];
    float tp1v = tp1[n*256 + t];
    ss[t]   = sv;
    tp0s[t] = tp0v;
    w1s[t]  = (1.f - tp0v*tp0v) * z2T[n*256 + t];
    w2s[t]  = (1.f - tp1v*tp1v) * wv[t];
    float tot = (1.f - sv*sv) * z1T[n*256 + t] * ksq[t];   // trH layer-0 partial (m=t)
    __syncthreads();

    // build Af: chunk q = dtile*1024 + kstep*64 + tl, tl = lane slot
    #pragma unroll
    for (int i = 0; i < 8; ++i) {
        int q = t + i*256;                 // 2048 lane-chunks of 8 ushorts
        int dtile = q >> 10, kstep = (q >> 6) & 15, tl = q & 63;
        int d = dtile*32 + (tl & 31);
        int m0 = kstep*16 + (tl >> 5)*8;
        short8 v8;
        if (d == 63) {
            #pragma unroll
            for (int e = 0; e < 8; ++e) v8[e] = 0;
        } else {
            const float* wp = &W0T[d*256 + m0];
            #pragma unroll
            for (int e = 0; e < 8; ++e) v8[e] = (short)f2bfu(wp[e] * ss[m0 + e]);
        }
        *reinterpret_cast<short8*>(&Af[q*8]) = v8;
    }
    __syncthreads();

    floatx16 acc[2][2];   // [d-tile c][a-tile j]

    // ---------------- layer 0: KJ1^T ----------------
    #pragma unroll
    for (int c = 0; c < 2; ++c)
        #pragma unroll
        for (int j = 0; j < 2; ++j)
            #pragma unroll
            for (int r = 0; r < 16; ++r) acc[c][j][r] = 0.f;

    for (int ks = 0; ks < 16; ++ks) {
        short8 Ah[2];
        #pragma unroll
        for (int c = 0; c < 2; ++c)
            Ah[c] = *reinterpret_cast<const short8*>(&Af[((c*16 + ks)*64 + lane)*8]);
        #pragma unroll
        for (int j = 0; j < 2; ++j) {
            const unsigned short* bp = FB + (((w*2 + j)*16 + ks)*2)*512 + lane*8;
            short8 Bh = *reinterpret_cast<const short8*>(bp);
            short8 Bl = *reinterpret_cast<const short8*>(bp + 512);
            #pragma unroll
            for (int c = 0; c < 2; ++c) {
                acc[c][j] = __builtin_amdgcn_mfma_f32_32x32x16_bf16(Ah[c], Bh, acc[c][j], 0, 0, 0);
                acc[c][j] = __builtin_amdgcn_mfma_f32_32x32x16_bf16(Ah[c], Bl, acc[c][j], 0, 0, 0);
            }
        }
    }
    __syncthreads();   // all layer-0 reads of Af done before update writes

    // trH layer-1 term + Jac update (LDS RMW in fragment slot):
    //   JacT[d][a] += 0.5*tp0[a]*KJ1T[d][a]
    {
        float w1a[2], tp0a[2]; int abase[2];
        #pragma unroll
        for (int j = 0; j < 2; ++j) {
            int a = (w*2 + j)*32 + l31;
            abase[j] = a;
            w1a[j]  = w1s[a];
            tp0a[j] = 0.5f * tp0s[a];
        }
        #pragma unroll
        for (int c = 0; c < 2; ++c)
            #pragma unroll
            for (int r = 0; r < 16; ++r) {
                int d = c*32 + (r & 3) + 8*(r >> 2) + 4*lhi;
                #pragma unroll
                for (int j = 0; j < 2; ++j) {
                    float v = acc[c][j][r];
                    tot += 0.5f * w1a[j] * v * v;
                    int a = abase[j];
                    int lslot = ((a >> 3) & 1)*32 + (d & 31);
                    int idx = (((d >> 5)*16 + (a >> 4))*64 + lslot)*8 + (a & 7);
                    Af[idx] = f2bfu(bfu2f(Af[idx]) + tp0a[j] * v);
                }
            }
    }
    __syncthreads();   // updates visible before layer-1 reads

    // ---------------- layer 1: KJ2^T ----------------
    #pragma unroll
    for (int c = 0; c < 2; ++c)
        #pragma unroll
        for (int j = 0; j < 2; ++j)
            #pragma unroll
            for (int r = 0; r < 16; ++r) acc[c][j][r] = 0.f;

    const unsigned short* FB1 = FB + 131072;
    for (int ks = 0; ks < 16; ++ks) {
        short8 Ah[2];
        #pragma unroll
        for (int c = 0; c < 2; ++c)
            Ah[c] = *reinterpret_cast<const short8*>(&Af[((c*16 + ks)*64 + lane)*8]);
        #pragma unroll
        for (int j = 0; j < 2; ++j) {
            const unsigned short* bp = FB1 + (((w*2 + j)*16 + ks)*2)*512 + lane*8;
            short8 Bh = *reinterpret_cast<const short8*>(bp);
            short8 Bl = *reinterpret_cast<const short8*>(bp + 512);
            #pragma unroll
            for (int c = 0; c < 2; ++c) {
                acc[c][j] = __builtin_amdgcn_mfma_f32_32x32x16_bf16(Ah[c], Bh, acc[c][j], 0, 0, 0);
                acc[c][j] = __builtin_amdgcn_mfma_f32_32x32x16_bf16(Ah[c], Bl, acc[c][j], 0, 0, 0);
            }
        }
    }

    // trH layer-2 term
    {
        #pragma unroll
        for (int j = 0; j < 2; ++j) {
            float w2a = w2s[(w*2 + j)*32 + l31];
            #pragma unroll
            for (int c = 0; c < 2; ++c)
                #pragma unroll
                for (int r = 0; r < 16; ++r) {
                    float v = acc[c][j][r];
                    tot += 0.5f * w2a * v * v;
                }
        }
    }

    // reduce 256 -> 1
    for (int off = 32; off; off >>= 1) tot += __shfl_down(tot, off, 64);
    if (lane == 0) red[w] = tot;
    __syncthreads();
    if (t == 0) outTrH[n] = red[0] + red[1] + red[2] + red[3] + trace[0];
}

// ---------------- launcher ----------------

extern "C" void kernel_launch(void* const* d_in, const int* in_sizes, int n_in,
                              void* d_out, int out_size, void* d_ws, size_t ws_size,
                              hipStream_t stream) {
    const float* x   = (const float*)d_in[0];   // 4096*64
    const float* W0  = (const float*)d_in[1];   // 256*64
    const float* b0  = (const float*)d_in[2];   // 256
    const float* Wd  = (const float*)d_in[3];   // 2*256*256
    const float* bd  = (const float*)d_in[4];   // 2*256
    const float* wv  = (const float*)d_in[5];   // 256
    const float* A   = (const float*)d_in[6];   // 10*64
    const float* cw  = (const float*)d_in[7];   // 64
    float* out = (float*)d_out;
    float* ws  = (float*)d_ws;

    float* tanhopen = ws;               // NM
    float* tp0  = tanhopen + NM;        // NM
    float* tp1  = tp0 + NM;             // NM
    float* z2T  = tp1 + NM;             // NM
    float* z1T  = z2T + NM;             // NM
    float* Wd0T = z1T + NM;             // 65536
    float* Wd1T = Wd0T + 65536;         // 65536
    float* W0T  = Wd1T + 65536;         // 16384
    float* symA = W0T + 16384;          // 4096
    float* ksq  = symA + 4096;          // 256
    float* trace= ksq + 256;            // 1
    unsigned short* FB = (unsigned short*)(trace + 1);    // 262144 ushorts (512 KB)

    k_prep<<<657, 256, 0, stream>>>(Wd, W0, A, FB, Wd0T, Wd1T, W0T,
                                    symA, ksq, trace);
    k_fwd<<<NEX/8, 256, 0, stream>>>(x, W0T, b0, Wd0T, Wd1T, bd,
                                     tanhopen, tp0, tp1);
    k_bwd<<<NEX/8, 256, 0, stream>>>(tanhopen, tp0, tp1, wv, Wd, W0, symA, x, cw,
                                     z2T, z1T, out);
    k_heavy_mfma<<<NEX, 256, 0, stream>>>(tanhopen, tp0, tp1, z2T, z1T, wv,
                                          W0T, FB, ksq, trace, out + NEX*64);
}